// Round 1
// baseline (1578.413 us; speedup 1.0000x reference)
//
#include <hip/hip_runtime.h>
#include <math.h>

#define N_ROWS 2048
#define D_DIM  128
#define N_CLS  100000
#define S_SCALE 64.0f
#define EPS_F   1e-7f
#define COS_M   0.8775825618903728f   // cos(0.5)
#define SIN_M   0.479425538604203f    // sin(0.5)
#define TR 64
#define TC 64

// Kernel 1: L2-normalize each row of x. One 64-lane wave per row, float2 per lane.
__global__ void k_normalize(const float* __restrict__ x, float* __restrict__ xn) {
    int row = blockIdx.x;
    int l = threadIdx.x;  // 0..63
    const float2* xr = reinterpret_cast<const float2*>(x + (size_t)row * D_DIM);
    float2 v = xr[l];
    float s = v.x * v.x + v.y * v.y;
    #pragma unroll
    for (int off = 1; off < 64; off <<= 1) s += __shfl_xor(s, off);
    float inv = 1.0f / sqrtf(s);
    float2 o; o.x = v.x * inv; o.y = v.y * inv;
    reinterpret_cast<float2*>(xn + (size_t)row * D_DIM)[l] = o;
}

// Kernel 2: fused tile-GEMM + exp + per-row partial sum.
// Block: 256 threads = 16x16 thread grid; tile 64 rows x 64 classes; K=128 staged
// once into LDS (float4, XOR-swizzled so class-strided b128 reads are conflict-free).
__global__ __launch_bounds__(256, 2)
void k_main(const float* __restrict__ xn, const float* __restrict__ W,
            float* __restrict__ rowsum) {
    __shared__ float4 xsh[64][32];
    __shared__ float4 wsh[64][32];
    int c0 = blockIdx.x * TC;
    int r0 = blockIdx.y * TR;
    int t = threadIdx.x;

    const float4* xg = reinterpret_cast<const float4*>(xn) + (size_t)r0 * 32;
    const float4* wg = reinterpret_cast<const float4*>(W) + (size_t)c0 * 32;
    #pragma unroll
    for (int i = 0; i < 8; i++) {
        int flat = t + i * 256;
        int r = flat >> 5, k4 = flat & 31;
        int sw = k4 ^ ((r >> 2) & 7);
        xsh[r][sw] = xg[flat];
        float4 wv = make_float4(0.f, 0.f, 0.f, 0.f);
        if (c0 + r < N_CLS) wv = wg[flat];
        wsh[r][sw] = wv;
    }
    __syncthreads();

    int tx = t & 15, ty = t >> 4;
    int xsw = ty & 7, wswz = tx & 7;
    float acc[4][4] = {};  // [row][class]

    #pragma unroll 8
    for (int k4 = 0; k4 < 32; k4++) {
        float4 a[4], b[4];
        #pragma unroll
        for (int j = 0; j < 4; j++) a[j] = xsh[4 * ty + j][k4 ^ xsw];
        #pragma unroll
        for (int j = 0; j < 4; j++) b[j] = wsh[4 * tx + j][k4 ^ wswz];
        #pragma unroll
        for (int i = 0; i < 4; i++)
            #pragma unroll
            for (int j = 0; j < 4; j++) {
                acc[i][j] += a[i].x * b[j].x + a[i].y * b[j].y
                           + a[i].z * b[j].z + a[i].w * b[j].w;
            }
    }

    // exp + per-row sums (reduce across the 16 tx lanes, low 4 bits of lane id)
    #pragma unroll
    for (int i = 0; i < 4; i++) {
        float p = 0.f;
        #pragma unroll
        for (int j = 0; j < 4; j++) {
            int c = c0 + 4 * tx + j;
            if (c < N_CLS) p += __expf(S_SCALE * acc[i][j]);
        }
        #pragma unroll
        for (int off = 1; off < 16; off <<= 1) p += __shfl_xor(p, off);
        if (tx == 0) atomicAdd(&rowsum[r0 + 4 * ty + i], p);
    }
}

// Kernel 3: target logit wf[i, y_i]. One wave per row.
__global__ void k_tgt(const float* __restrict__ xn, const float* __restrict__ W,
                      const int* __restrict__ labels, float* __restrict__ tgt) {
    int row = blockIdx.x;
    int l = threadIdx.x;  // 0..63
    int y = labels[row];
    const float2* xr = reinterpret_cast<const float2*>(xn + (size_t)row * D_DIM);
    const float2* wr = reinterpret_cast<const float2*>(W + (size_t)y * D_DIM);
    float2 a = xr[l], b = wr[l];
    float s = a.x * b.x + a.y * b.y;
    #pragma unroll
    for (int off = 1; off < 64; off <<= 1) s += __shfl_xor(s, off);
    if (l == 0) tgt[row] = s;
}

// Kernel 4: per-row loss + mean. Single block.
__global__ void k_final(const float* __restrict__ rowsum, const float* __restrict__ tgt,
                        float* __restrict__ out) {
    int t = threadIdx.x;
    float lsum = 0.f;
    for (int i = t; i < N_ROWS; i += 256) {
        float tr = tgt[i];
        float tc = fminf(fmaxf(tr, -1.f + EPS_F), 1.f - EPS_F);
        float num = S_SCALE * (tc * COS_M - sqrtf(fmaxf(1.f - tc * tc, 0.f)) * SIN_M);
        float excl = rowsum[i] - __expf(S_SCALE * tr);
        float den = __expf(num) + excl;
        lsum += num - logf(den);
    }
    #pragma unroll
    for (int off = 1; off < 64; off <<= 1) lsum += __shfl_xor(lsum, off);
    __shared__ float wsums[4];
    if ((t & 63) == 0) wsums[t >> 6] = lsum;
    __syncthreads();
    if (t == 0) out[0] = -(wsums[0] + wsums[1] + wsums[2] + wsums[3]) / (float)N_ROWS;
}

extern "C" void kernel_launch(void* const* d_in, const int* in_sizes, int n_in,
                              void* d_out, int out_size, void* d_ws, size_t ws_size,
                              hipStream_t stream) {
    const float* x = (const float*)d_in[0];
    const float* W = (const float*)d_in[1];
    const int* labels = (const int*)d_in[2];
    float* out = (float*)d_out;

    float* xn     = (float*)d_ws;               // N*D floats
    float* rowsum = xn + (size_t)N_ROWS * D_DIM; // N floats
    float* tgt    = rowsum + N_ROWS;             // N floats

    hipMemsetAsync(rowsum, 0, N_ROWS * sizeof(float), stream);
    k_normalize<<<N_ROWS, 64, 0, stream>>>(x, xn);
    dim3 grid((N_CLS + TC - 1) / TC, N_ROWS / TR);
    k_main<<<grid, 256, 0, stream>>>(xn, W, rowsum);
    k_tgt<<<N_ROWS, 64, 0, stream>>>(xn, W, labels, tgt);
    k_final<<<1, 256, 0, stream>>>(rowsum, tgt, out);
}

// Round 2
// 144.485 us; speedup vs baseline: 10.9244x; 10.9244x over previous
//
#include <hip/hip_runtime.h>
#include <math.h>

typedef __attribute__((ext_vector_type(8))) short s16x8;
typedef __attribute__((ext_vector_type(4))) float f32x4;

#define N_ROWS 2048
#define D_DIM  128
#define N_CLS  100000
#define S_SCALE 64.0f
#define S_LOG2E 92.33248261689366f   // 64 * log2(e)
#define EPS_F   1e-7f
#define COS_M   0.8775825618903728f  // cos(0.5)
#define SIN_M   0.479425538604203f   // sin(0.5)

__device__ __forceinline__ unsigned int f2bf1(float f) {
    unsigned int u = __float_as_uint(f);
    return (u + 0x7FFFu + ((u >> 16) & 1u)) >> 16;   // RNE, inputs are normal floats
}
__device__ __forceinline__ unsigned int f2bf2(float lo, float hi) {
    return f2bf1(lo) | (f2bf1(hi) << 16);
}

// Kernel 1: L2-normalize rows of x; write fp32 (for target path) and bf16 (for MFMA).
__global__ void k_normalize(const float* __restrict__ x, float* __restrict__ xn,
                            unsigned int* __restrict__ xb) {
    int row = blockIdx.x;
    int l = threadIdx.x;  // 0..63
    const float2* xr = reinterpret_cast<const float2*>(x + (size_t)row * D_DIM);
    float2 v = xr[l];
    float s = v.x * v.x + v.y * v.y;
    #pragma unroll
    for (int off = 1; off < 64; off <<= 1) s += __shfl_xor(s, off);
    float inv = 1.0f / sqrtf(s);
    float2 o; o.x = v.x * inv; o.y = v.y * inv;
    reinterpret_cast<float2*>(xn + (size_t)row * D_DIM)[l] = o;
    xb[(size_t)row * 64 + l] = f2bf2(o.x, o.y);   // 2 bf16 per lane, row-major [2048][128]
}

// Kernel 2: MFMA GEMM (swapped: A = W tile [classes x K], B = xn [K x rows]) fused
// with exp2 + per-x-row partial sums. One block owns one 128-class tile (W converted
// fp32->bf16 into LDS once) and iterates 8 row-tiles of its half of x.
__global__ __launch_bounds__(256, 2)
void k_main(const unsigned int* __restrict__ xb, const float* __restrict__ W,
            float* __restrict__ rowsum) {
    __shared__ uint4 Wsh[128][16];  // [class][k-chunk^swz], 8 bf16 per chunk
    __shared__ uint4 Ash[128][16];  // [x-row][k-chunk^swz]
    const int t = threadIdx.x;
    const int c0 = blockIdx.y * 128;   // class tile base
    const int half = blockIdx.x;       // row half (0/1)

    // ---- stage + convert W tile (once per block) ----
    #pragma unroll
    for (int i = 0; i < 8; i++) {
        int f = t + i * 256;            // chunk id 0..2047
        int r = f >> 4, c = f & 15;
        uint4 val = make_uint4(0u, 0u, 0u, 0u);
        int cls = c0 + r;
        if (cls < N_CLS) {
            const f32x4* g = (const f32x4*)(W + (size_t)cls * D_DIM + c * 8);
            f32x4 f0 = g[0], f1 = g[1];
            val.x = f2bf2(f0[0], f0[1]);
            val.y = f2bf2(f0[2], f0[3]);
            val.z = f2bf2(f1[0], f1[1]);
            val.w = f2bf2(f1[2], f1[3]);
        }
        Wsh[r][c ^ (r & 7)] = val;
    }

    const int lane = t & 63;
    const int wid  = t >> 6;
    const int wm = wid >> 1;     // class half within tile (0/1)
    const int wn = wid & 1;      // x-row half within tile (0/1)
    const int lr = lane & 15;
    const int lk = lane >> 4;

    // class-validity mask, constant across row iterations (classes sit in reg dim)
    float clsmask[4][4];
    #pragma unroll
    for (int i = 0; i < 4; i++)
        #pragma unroll
        for (int r = 0; r < 4; r++)
            clsmask[i][r] = (c0 + wm * 64 + i * 16 + lk * 4 + r < N_CLS) ? 1.0f : 0.0f;

    for (int it = 0; it < 8; it++) {
        const int r0 = half * 1024 + it * 128;
        __syncthreads();   // previous iter's readers done before Ash rewrite
        #pragma unroll
        for (int i = 0; i < 8; i++) {
            int f = t + i * 256;
            int r = f >> 4, c = f & 15;
            Ash[r][c ^ (r & 7)] = ((const uint4*)xb)[(size_t)(r0 + r) * 16 + c];
        }
        __syncthreads();

        f32x4 acc[4][4];
        #pragma unroll
        for (int i = 0; i < 4; i++)
            #pragma unroll
            for (int j = 0; j < 4; j++)
                acc[i][j] = (f32x4){0.f, 0.f, 0.f, 0.f};

        #pragma unroll
        for (int ks = 0; ks < 4; ks++) {
            const int ck = ks * 4 + lk;
            s16x8 a[4], b[4];
            #pragma unroll
            for (int i = 0; i < 4; i++) {
                int row = wm * 64 + i * 16 + lr;              // class index in tile
                a[i] = *(const s16x8*)&Wsh[row][ck ^ (row & 7)];
            }
            #pragma unroll
            for (int j = 0; j < 4; j++) {
                int col = wn * 64 + j * 16 + lr;              // x-row index in tile
                b[j] = *(const s16x8*)&Ash[col][ck ^ (col & 7)];
            }
            #pragma unroll
            for (int i = 0; i < 4; i++)
                #pragma unroll
                for (int j = 0; j < 4; j++)
                    acc[i][j] = __builtin_amdgcn_mfma_f32_16x16x32_bf16(
                        a[i], b[j], acc[i][j], 0, 0, 0);
        }

        // epilogue: D[class][xrow]; lane holds xrow = wn*64+j*16+lr, classes in regs.
        // exp-sum over classes is in-lane except a 4-way lk reduction (2 shfls).
        #pragma unroll
        for (int j = 0; j < 4; j++) {
            float pj = 0.f;
            #pragma unroll
            for (int i = 0; i < 4; i++)
                #pragma unroll
                for (int r = 0; r < 4; r++)
                    pj += clsmask[i][r] * exp2f(S_LOG2E * acc[i][j][r]);
            pj += __shfl_xor(pj, 16);
            pj += __shfl_xor(pj, 32);
            if (lk == 0)
                atomicAdd(&rowsum[r0 + wn * 64 + j * 16 + lr], pj);
        }
    }
}

// Kernel 3: target logit wf[i, y_i] in fp32 (feeds the arccos margin path).
__global__ void k_tgt(const float* __restrict__ xn, const float* __restrict__ W,
                      const int* __restrict__ labels, float* __restrict__ tgt) {
    int row = blockIdx.x;
    int l = threadIdx.x;
    int y = labels[row];
    const float2* xr = reinterpret_cast<const float2*>(xn + (size_t)row * D_DIM);
    const float2* wr = reinterpret_cast<const float2*>(W + (size_t)y * D_DIM);
    float2 a = xr[l], b = wr[l];
    float s = a.x * b.x + a.y * b.y;
    #pragma unroll
    for (int off = 1; off < 64; off <<= 1) s += __shfl_xor(s, off);
    if (l == 0) tgt[row] = s;
}

// Kernel 4: per-row loss + mean. Single block.
__global__ void k_final(const float* __restrict__ rowsum, const float* __restrict__ tgt,
                        float* __restrict__ out) {
    int t = threadIdx.x;
    float lsum = 0.f;
    for (int i = t; i < N_ROWS; i += 256) {
        float tr = tgt[i];
        float tc = fminf(fmaxf(tr, -1.f + EPS_F), 1.f - EPS_F);
        float num = S_SCALE * (tc * COS_M - sqrtf(fmaxf(1.f - tc * tc, 0.f)) * SIN_M);
        float excl = rowsum[i] - __expf(S_SCALE * tr);
        float den = __expf(num) + excl;
        lsum += num - logf(den);
    }
    #pragma unroll
    for (int off = 1; off < 64; off <<= 1) lsum += __shfl_xor(lsum, off);
    __shared__ float wsums[4];
    if ((t & 63) == 0) wsums[t >> 6] = lsum;
    __syncthreads();
    if (t == 0) out[0] = -(wsums[0] + wsums[1] + wsums[2] + wsums[3]) / (float)N_ROWS;
}

extern "C" void kernel_launch(void* const* d_in, const int* in_sizes, int n_in,
                              void* d_out, int out_size, void* d_ws, size_t ws_size,
                              hipStream_t stream) {
    const float* x = (const float*)d_in[0];
    const float* W = (const float*)d_in[1];
    const int* labels = (const int*)d_in[2];
    float* out = (float*)d_out;

    float* xn            = (float*)d_ws;                       // N*D fp32
    unsigned int* xb     = (unsigned int*)(xn + (size_t)N_ROWS * D_DIM); // N*D bf16 (as u32 pairs)
    float* rowsum        = (float*)(xb + (size_t)N_ROWS * D_DIM / 2);    // N fp32
    float* tgt           = rowsum + N_ROWS;                              // N fp32

    hipMemsetAsync(rowsum, 0, N_ROWS * sizeof(float), stream);
    k_normalize<<<N_ROWS, 64, 0, stream>>>(x, xn, xb);
    dim3 grid(2, (N_CLS + 127) / 128);
    k_main<<<grid, 256, 0, stream>>>(xb, W, rowsum);
    k_tgt<<<N_ROWS, 64, 0, stream>>>(xn, W, labels, tgt);
    k_final<<<1, 256, 0, stream>>>(rowsum, tgt, out);
}